// Round 8
// baseline (123.177 us; speedup 1.0000x reference)
//
#include <hip/hip_runtime.h>
#include <hip/hip_bf16.h>

#define S_LEN 4096
#define DHD   64
#define NH    16
#define NKT   64          // max k-tiles of 64
#define KVB   64
#define WQ    32          // q rows per wave
#define QB    128         // q rows per block (4 wave-pairs x 32)
// scale = 1/sqrt(64) = 0.125, folded with log2(e) so softmax runs in base-2 domain
#define QSCALE 0.18033688011112042f
#define THRS   8.656170245333781f   // defer-max threshold: 6 nats in log2 domain

#if __has_builtin(__builtin_amdgcn_exp2f)
#define EXP2(x) __builtin_amdgcn_exp2f(x)
#else
#define EXP2(x) exp2f(x)
#endif

typedef __bf16 bf16x8 __attribute__((ext_vector_type(8)));
typedef __bf16 bf16x4 __attribute__((ext_vector_type(4)));
typedef float  f32x16 __attribute__((ext_vector_type(16)));
typedef float  f32x4  __attribute__((ext_vector_type(4)));
typedef unsigned u32;
typedef unsigned u32x4v __attribute__((ext_vector_type(4)));
typedef unsigned long long u64;

#define MFMA32 __builtin_amdgcn_mfma_f32_32x32x16_bf16

// XOR swizzle (G4): element = row*64 + (((col>>3) ^ (row&7))<<3 | (col&7))
__device__ __forceinline__ int swz(int row, int col) {
  return row * 64 + ((((col >> 3) ^ (row & 7)) << 3) | (col & 7));
}

__device__ __forceinline__ u32 pk(float a, float b) {   // pack 2 f32 -> 2 bf16 (RNE)
  __bf16 x = (__bf16)a, y = (__bf16)b;
  u32 lo = (u32)__builtin_bit_cast(unsigned short, x);
  u32 hi = (u32)__builtin_bit_cast(unsigned short, y);
  return lo | (hi << 16);
}

__device__ __forceinline__ void gload16(const void* g, void* l) {
  __builtin_amdgcn_global_load_lds((const __attribute__((address_space(1))) void*)g,
                                   (__attribute__((address_space(3))) void*)l, 16, 0, 0);
}

// v_permlane32_swap_b32: x.hi <-> y.lo across the lane<32 / lane>=32 halves.
__device__ __forceinline__ void plswap(u32& x, u32& y) {
  asm("v_permlane32_swap_b32 %0, %1" : "+v"(x), "+v"(y));
}

union PAW { u32x4v w; bf16x8 h; };

template <int MODE>
__device__ __forceinline__ bool patget(const void* __restrict__ p, int q, int k) {
  const size_t idx = (size_t)q * S_LEN + k;
  if constexpr (MODE == 1) return ((const unsigned char*)p)[idx] != 0;
  else if constexpr (MODE == 0) return ((const int*)p)[idx] != 0;
  else return ((const float*)p)[idx] != 0.0f;
}

// ===================== compacted-key main kernel (8-wave, K-split x2) =====================
// K/V pre-gathered (mask-surviving keys only), bf16, PRE-SWIZZLED tile layout (rule #21).
// 8 waves: group A (waves 0-3) takes even tiles, group B (waves 4-7) odd tiles, each with
// its own double-buffered LDS stream. Final flash-merge of (O,l,m) through LDS (no HBM).
// Per wave per iter: 1 pw load + 4 gload_lds -> counted vmcnt(5) + raw barriers (T4).
__global__ void __launch_bounds__(512, 4) attn32c(
    const float* __restrict__ Qg, const __bf16* __restrict__ Kc, const __bf16* __restrict__ Vc,
    const u64* __restrict__ packw,            // [w][q] bit j = pat(q, key(w*64+j))
    const int* __restrict__ mask, float* __restrict__ out) {
  __shared__ __align__(16) char smem[65536];  // K/V streams; reused as merge buffer
  __shared__ float sfb[8][WQ];
  __shared__ int msum[8];
  __bf16* Kls = (__bf16*)smem;                // [(grp*2+buf)][4096]
  __bf16* Vls = (__bf16*)(smem + 32768);

  // XCD-chunked block swizzle: each XCD owns 2 consecutive heads (K/V L2-resident)
  const int gid = (blockIdx.x & 7) * 64 + (blockIdx.x >> 3);
  const int h = gid >> 5;
  const int q0 = (gid & 31) * QB;

  const int t = threadIdx.x, lane = t & 63, wv = t >> 6;
  const int grp = wv >> 2, ws = wv & 3;       // K-split group; wave-pair slot
  const int l32 = lane & 31, hi = lane >> 5;
  const int qrow = q0 + ws * WQ + l32;

  // ---- self-compute active-key count from mask (16KB, L2-hot) ----
  int c = 0;
#pragma unroll
  for (int j = 0; j < 8; j++) c += (mask[t * 8 + j] != 0);
#pragma unroll
  for (int d = 1; d < 64; d <<= 1) c += __shfl_xor(c, d);
  if (lane == 0) msum[wv] = c;

  // Q B-fragments: aQ[cc] elem j = Q[qrow][cc*16 + hi*8 + j] * QSCALE
  bf16x8 aQ[4];
  {
    const float* qp = Qg + ((size_t)h * S_LEN + qrow) * DHD;
#pragma unroll
    for (int cc = 0; cc < 4; cc++) {
      float4 x = *(const float4*)(qp + cc * 16 + hi * 8);
      float4 y = *(const float4*)(qp + cc * 16 + hi * 8 + 4);
      bf16x8 f;
      f[0] = (__bf16)(x.x * QSCALE); f[1] = (__bf16)(x.y * QSCALE);
      f[2] = (__bf16)(x.z * QSCALE); f[3] = (__bf16)(x.w * QSCALE);
      f[4] = (__bf16)(y.x * QSCALE); f[5] = (__bf16)(y.y * QSCALE);
      f[6] = (__bf16)(y.z * QSCALE); f[7] = (__bf16)(y.w * QSCALE);
      aQ[cc] = f;
    }
  }
  bf16x8 onesf;
#pragma unroll
  for (int j = 0; j < 8; j++) onesf[j] = (__bf16)1.0f;
  f32x16 zv;
#pragma unroll
  for (int r = 0; r < 16; r++) zv[r] = 0.f;

  __syncthreads();
  int nact = 0;
#pragma unroll
  for (int w = 0; w < 8; w++) nact += msum[w];
  const int nt = (nact + 63) >> 6;
  const int nte = (nt + 1) & ~1;        // even-padded (pad tiles are zeros, bits 0)
  const int nh = nte >> 1;              // iterations per group

  const __bf16* Kb = Kc + (size_t)h * NKT * 4096;
  const __bf16* Vb = Vc + (size_t)h * NKT * 4096;

  auto stage = [&](int buf, int kt) {
    const __bf16* kbase = Kb + (size_t)kt * 4096;
    const __bf16* vbase = Vb + (size_t)kt * 4096;
    const int s = (grp * 2 + buf) * 4096;
#pragma unroll
    for (int i = 0; i < 2; i++) {
      const int j = ws * 2 + i;           // chunk 0..7 of 512 elems (1KB)
      gload16(kbase + j * 512 + lane * 8, &Kls[s + j * 512]);
      gload16(vbase + j * 512 + lane * 8, &Vls[s + j * 512]);
    }
  };

  f32x16 Oc0 = zv, Oc1 = zv, Ol = zv;
  float m_run = -__builtin_inff();
  const u64* prow = packw + qrow;

  __builtin_amdgcn_sched_barrier(0);
  // prologue: this group's first tile (1 pw load + 4 gload_lds in flight)
  u64 pw = prow[(size_t)grp * S_LEN];
  u64 pw_n = 0;
  stage(0, grp);
  int buf = 0;

  for (int it = 0; it < nh; it++) {
    if (it + 1 < nh) {
      const int ktn = 2 * it + 2 + grp;
      pw_n = prow[(size_t)ktn * S_LEN];    // issued BEFORE the stage gloads
      stage(buf ^ 1, ktn);
      asm volatile("s_waitcnt vmcnt(5)" ::: "memory");  // prev iter's 5 vmem done
    } else {
      asm volatile("s_waitcnt vmcnt(0)" ::: "memory");
    }
    __builtin_amdgcn_s_barrier();
    __builtin_amdgcn_sched_barrier(0);   // rule #18

    const __bf16* Kl = &Kls[(grp * 2 + buf) * 4096];
    const __bf16* Vl = &Vls[(grp * 2 + buf) * 4096];

    // ---- S^T = K Q^T: p0 = k rows 0..31, p1 = 32..63; lane owns q = l32 ----
    f32x16 p0, p1;
    __builtin_amdgcn_s_setprio(1);
#pragma unroll
    for (int cc = 0; cc < 4; cc++) {
      const int g = (((2 * cc + hi) ^ (l32 & 7)) << 3);
      const bf16x8 k0 = *(const bf16x8*)&Kl[l32 * 64 + g];
      const bf16x8 k1 = *(const bf16x8*)&Kl[(32 + l32) * 64 + g];
      p0 = MFMA32(k0, aQ[cc], cc ? p0 : zv, 0, 0, 0);
      p1 = MFMA32(k1, aQ[cc], cc ? p1 : zv, 0, 0, 0);
    }
    __builtin_amdgcn_s_setprio(0);

    // ---- tree max (depth 5) over raw scores ----
    float mx[16];
#pragma unroll
    for (int i = 0; i < 8; i++) {
      mx[i]     = fmaxf(p0[2 * i], p0[2 * i + 1]);
      mx[8 + i] = fmaxf(p1[2 * i], p1[2 * i + 1]);
    }
#pragma unroll
    for (int s = 8; s >= 1; s >>= 1)
#pragma unroll
      for (int i = 0; i < s; i++) mx[i] = fmaxf(mx[i], mx[i + s]);
    const float pm = fmaxf(mx[0], __shfl_xor(mx[0], 32));

    if (!__all(pm <= m_run + THRS)) {   // defer-max (T13)
      const float mn = fmaxf(m_run, pm);
      const float sf = EXP2(m_run - mn);
      m_run = mn;
      if (lane < 32) sfb[wv][l32] = sf;
#pragma unroll
      for (int rq = 0; rq < 4; rq++) {   // transpose sf into C-layout rows (wave-private)
        const f32x4 s4 = *(const f32x4*)&sfb[wv][rq * 8 + 4 * hi];
#pragma unroll
        for (int rr = 0; rr < 4; rr++) {
          Oc0[rq * 4 + rr] *= s4[rr];
          Oc1[rq * 4 + rr] *= s4[rr];
          Ol[rq * 4 + rr]  *= s4[rr];
        }
      }
    }

    // pattern bits, shifted for this lane half: element (ksub,sp) = bit 32*ksub + sp + 4*hi
    const u32 b0 = (u32)pw, b1 = (u32)(pw >> 32);
    const u32 w0 = hi ? ((b0 >> 4) | (b1 << 28)) : b0;
    const u32 w1 = hi ? (b1 >> 4) : b1;

#pragma unroll
    for (int r = 0; r < 16; r++) {
      const int sp = (r & 3) + 8 * (r >> 2);
      float e0 = EXP2(p0[r] - m_run);
      float e1 = EXP2(p1[r] - m_run);
      const int t0 = (int)(w0 << (31 - sp)) >> 31;   // bit -> all-ones / 0
      const int t1 = (int)(w1 << (31 - sp)) >> 31;
      p0[r] = __uint_as_float(__float_as_uint(e0) & (u32)t0);
      p1[r] = __uint_as_float(__float_as_uint(e1) & (u32)t1);
    }

    // ---- P -> bf16 A-frags via pack + permlane32_swap; PV + l via MFMA-ones ----
    __builtin_amdgcn_s_setprio(1);
#pragma unroll
    for (int ks = 0; ks < 4; ks++) {
      const f32x16& ps = (ks < 2) ? p0 : p1;
      const int b = (ks & 1) * 8;
      u32 x0 = pk(ps[b + 0], ps[b + 1]), x1 = pk(ps[b + 2], ps[b + 3]);
      u32 y0 = pk(ps[b + 4], ps[b + 5]), y1 = pk(ps[b + 6], ps[b + 7]);
      plswap(x0, y0);
      plswap(x1, y1);
      PAW pa;
      pa.w = (u32x4v){x0, x1, y0, y1};
      const int g = (((2 * ks + hi) ^ (l32 & 7)) << 3);
      const bf16x8 v0 = *(const bf16x8*)&Vl[l32 * 64 + g];
      const bf16x8 v1 = *(const bf16x8*)&Vl[(32 + l32) * 64 + g];
      Oc0 = MFMA32(pa.h, v0, Oc0, 0, 0, 0);
      Oc1 = MFMA32(pa.h, v1, Oc1, 0, 0, 0);
      Ol  = MFMA32(pa.h, onesf, Ol, 0, 0, 0);
    }
    __builtin_amdgcn_s_setprio(0);

    __builtin_amdgcn_s_barrier();   // group's waves done reading buf before re-stage
    buf ^= 1;
    pw = pw_n;
  }

  // ---- flash-merge A<-B through LDS (K/V buffers dead; stride 49 = conflict-free) ----
  float* cbuf = (float*)smem;
  float* cb = cbuf + (ws * 64 + lane) * 49;
  if (grp == 1) {
#pragma unroll
    for (int r = 0; r < 16; r++) {
      cb[r] = Oc0[r]; cb[16 + r] = Oc1[r]; cb[32 + r] = Ol[r];
    }
    if (lane < 32) sfb[4 + ws][l32] = m_run;
  } else {
    if (lane < 32) sfb[ws][l32] = m_run;
  }
  __syncthreads();
  if (grp == 0) {
    float* ob = out + ((size_t)h * S_LEN + q0 + ws * WQ) * DHD;
#pragma unroll
    for (int rq = 0; rq < 4; rq++) {
      const f32x4 a4 = *(const f32x4*)&sfb[ws][rq * 8 + 4 * hi];
      const f32x4 b4 = *(const f32x4*)&sfb[4 + ws][rq * 8 + 4 * hi];
#pragma unroll
      for (int rr = 0; rr < 4; rr++) {
        const int r = rq * 4 + rr;
        const float mm = fmaxf(a4[rr], b4[rr]);
        const float sa = EXP2(a4[rr] - mm);
        const float sb = EXP2(b4[rr] - mm);
        const float den = Ol[r] * sa + cb[32 + r] * sb;
        const float linv = 1.0f / den;
        const int qq = rr + 8 * rq + 4 * hi;
        ob[(size_t)qq * DHD + l32]      = (Oc0[r] * sa + cb[r] * sb) * linv;
        ob[(size_t)qq * DHD + 32 + l32] = (Oc1[r] * sa + cb[16 + r] * sb) * linv;
      }
    }
  }
}

// ===================== single merged prep kernel =====================
// blocks [0, S_LEN): pattern-bit pack for q-row b (self dtype-detect, LDS-staged row).
// blocks [S_LEN, S_LEN+NKT*NH): K/V gather -> bf16 -> pre-swizzled tiles (+ zero pad tile).
__global__ void __launch_bounds__(256) prep_all(
    const unsigned* __restrict__ pat32, const int* __restrict__ mask,
    const float* __restrict__ K, const float* __restrict__ V,
    u64* __restrict__ packw, __bf16* __restrict__ Kc, __bf16* __restrict__ Vc) {
  __shared__ int idxs[S_LEN];          // 16 KB
  __shared__ int red8[8];
  __shared__ __align__(16) unsigned rowbuf[4096];   // 16 KB
  const int t = threadIdx.x, lane = t & 63, wv = t >> 6;

  // ---- active-key prefix list ----
  unsigned mb = 0;
#pragma unroll
  for (int j = 0; j < 16; j++) mb |= (unsigned)(mask[t * 16 + j] != 0) << j;
  const int cnt = __builtin_popcount(mb);
  int inc = cnt;
  for (int d = 1; d < 64; d <<= 1) {
    const int v = __shfl_up(inc, d);
    if (lane >= d) inc += v;
  }
  if (lane == 63) red8[wv] = inc;
  __syncthreads();
  int base = 0;
  for (int w = 0; w < wv; w++) base += red8[w];
  const int nact = red8[0] + red8[1] + red8[2] + red8[3];
  int pfx = base + inc - cnt;
#pragma unroll
  for (int j = 0; j < 16; j++)
    if ((mb >> j) & 1) idxs[pfx++] = t * 16 + j;
  __syncthreads();
  const int nt = (nact + 63) >> 6;
  const int nte = (nt + 1) & ~1;       // padded to even, <= 64

  if (blockIdx.x < S_LEN) {
    // ---- pattern pack ----
    const int q = blockIdx.x;
    unsigned acc = 0;
    for (int i = t; i < 4096; i += 256) {
      const unsigned w = pat32[i];
      if (w == 0x3F800000u) acc |= 2u;
      else if (w & 0xFFFFFF00u) acc |= 1u;
    }
    for (int d = 1; d < 64; d <<= 1) acc |= (unsigned)__shfl_xor((int)acc, d);
    if (lane == 0) red8[4 + wv] = (int)acc;
    __syncthreads();
    acc = (unsigned)(red8[4] | red8[5] | red8[6] | red8[7]);
    const int mode = (acc & 2u) ? 2 : ((acc & 1u) ? 1 : 0);

    if (mode == 1) {
      const uint4* src = (const uint4*)((const unsigned char*)pat32 + ((size_t)q << 12));
      ((uint4*)rowbuf)[t] = src[t];                         // 4096 B
    } else {
      const uint4* src = (const uint4*)(pat32 + ((size_t)q << 12));
#pragma unroll
      for (int i = 0; i < 4; i++) ((uint4*)rowbuf)[t + 256 * i] = src[t + 256 * i];  // 16 KB
    }
    __syncthreads();
    const unsigned char* rb = (const unsigned char*)rowbuf;
    const int nkw = nte * 64;          // include zero words for the pad tile
    for (int bs = 0; bs < nkw; bs += 256) {
      const int j = bs + t;
      bool pb = false;
      if (j < nact) {
        const int k = idxs[j];
        pb = (mode == 1) ? (rb[k] != 0) : (rowbuf[k] != 0);
      }
      const u64 b = __ballot(pb);
      if ((t & 63) == 0) packw[(size_t)(j >> 6) * S_LEN + q] = b;
    }
  } else {
    // ---- K/V gather ----
    const int bb = blockIdx.x - S_LEN;
    const int kt = bb & 63, h = bb >> 6;
    if (kt >= nte) return;             // pad tile (kt = nte-1 when nt odd) IS written (zeros)
    __bf16* Kd = Kc + ((size_t)(h * NKT + kt)) * 4096;
    __bf16* Vd = Vc + ((size_t)(h * NKT + kt)) * 4096;
    const float* Kb = K + (size_t)h * S_LEN * DHD;
    const float* Vb = V + (size_t)h * S_LEN * DHD;
#pragma unroll
    for (int i = 0; i < 4; i++) {
      const int u = t + 256 * i;
      const int kk = u >> 4, d = (u & 15) * 4;
      const int kg = kt * 64 + kk;
      float4 v = {0.f, 0.f, 0.f, 0.f};
      if (kg < nact) v = *(const float4*)(Kb + (size_t)idxs[kg] * DHD + d);
      bf16x4 b;
      b[0] = (__bf16)v.x; b[1] = (__bf16)v.y; b[2] = (__bf16)v.z; b[3] = (__bf16)v.w;
      *(bf16x4*)&Kd[swz(kk, d)] = b;
    }
#pragma unroll
    for (int i = 0; i < 2; i++) {
      const int u = t + 256 * i;
      const int kp = u & 31, d4 = u >> 5;
      const int g0 = kt * 64 + 2 * kp, g1 = g0 + 1;
      float4 a = {0.f, 0.f, 0.f, 0.f}, b = {0.f, 0.f, 0.f, 0.f};
      if (g0 < nact) a = *(const float4*)(Vb + (size_t)idxs[g0] * DHD + d4 * 4);
      if (g1 < nact) b = *(const float4*)(Vb + (size_t)idxs[g1] * DHD + d4 * 4);
      const float* A = reinterpret_cast<const float*>(&a);
      const float* B = reinterpret_cast<const float*>(&b);
#pragma unroll
      for (int j = 0; j < 4; j++) {
        *(u32*)&Vd[swz(d4 * 4 + j, 2 * kp)] = pk(A[j], B[j]);
      }
    }
  }
}

// ===================== fallback (R6, proven): full-key in-loop staging, 4 waves =====================
template <bool PACKED, int MODE>
__global__ void __launch_bounds__(256, 2) attn32(
    const float* __restrict__ Qg, const float* __restrict__ Kg, const float* __restrict__ Vg,
    const u64* __restrict__ packw, const void* __restrict__ pat, const int* __restrict__ mask,
    float* __restrict__ out) {
  __shared__ __align__(16) __bf16 Kls[2][KVB * DHD];
  __shared__ __align__(16) __bf16 Vls[2][DHD * KVB];
  __shared__ float sfb[4][WQ];
  const int gid = (blockIdx.x & 7) * 64 + (blockIdx.x >> 3);
  const int h = gid >> 5;
  const int q0 = (gid & 31) * QB;
  const int t = threadIdx.x, lane = t & 63, wv = t >> 6;
  const int l32 = lane & 31, hi = lane >> 5;
  const int qrow = q0 + wv * WQ + l32;
  bf16x8 aQ[4];
  {
    const float* qp = Qg + ((size_t)h * S_LEN + qrow) * DHD;
#pragma unroll
    for (int cc = 0; cc < 4; cc++) {
      float4 x = *(const float4*)(qp + cc * 16 + hi * 8);
      float4 y = *(const float4*)(qp + cc * 16 + hi * 8 + 4);
      bf16x8 f;
      f[0] = (__bf16)(x.x * QSCALE); f[1] = (__bf16)(x.y * QSCALE);
      f[2] = (__bf16)(x.z * QSCALE); f[3] = (__bf16)(x.w * QSCALE);
      f[4] = (__bf16)(y.x * QSCALE); f[5] = (__bf16)(y.y * QSCALE);
      f[6] = (__bf16)(y.z * QSCALE); f[7] = (__bf16)(y.w * QSCALE);
      aQ[cc] = f;
    }
  }
  const float* Kb = Kg + (size_t)h * S_LEN * DHD;
  const float* Vb = Vg + (size_t)h * S_LEN * DHD;
  float4 kreg[4], vreg0[2], vreg1[2];
  auto issue_loads = [&](int kt) {
    const float* kbase = Kb + (size_t)kt * KVB * DHD;
    const float* vbase = Vb + (size_t)kt * KVB * DHD;
#pragma unroll
    for (int i = 0; i < 4; i++) {
      const int u = t + 256 * i;
      kreg[i] = *(const float4*)(kbase + (size_t)(u >> 4) * DHD + (u & 15) * 4);
    }
#pragma unroll
    for (int i = 0; i < 2; i++) {
      const int u = t + 256 * i;
      const int kp = u & 31, d4 = u >> 5;
      vreg0[i] = *(const float4*)(vbase + (size_t)(2 * kp) * DHD + d4 * 4);
      vreg1[i] = *(const float4*)(vbase + (size_t)(2 * kp + 1) * DHD + d4 * 4);
    }
  };
  auto write_tile = [&](int buf) {
    __bf16* Kd = Kls[buf];
    __bf16* Vd = Vls[buf];
#pragma unroll
    for (int i = 0; i < 4; i++) {
      const int u = t + 256 * i;
      const int kk = u >> 4, d = (u & 15) * 4;
      const float4 v = kreg[i];
      bf16x4 b;
      b[0] = (__bf16)v.x; b[1] = (__bf16)v.y; b[2] = (__bf16)v.z; b[3] = (__bf16)v.w;
      *(bf16x4*)&Kd[swz(kk, d)] = b;
    }
#pragma unroll
    for (int i = 0; i < 2; i++) {
      const int u = t + 256 * i;
      const int kp = u & 31, d4 = u >> 5;
      const float* A = reinterpret_cast<const float*>(&vreg0[i]);
      const float* B = reinterpret_cast<const float*>(&vreg1[i]);
#pragma unroll
      for (int j = 0; j < 4; j++) {
        *(u32*)&Vd[swz(d4 * 4 + j, 2 * kp)] = pk(A[j], B[j]);
      }
    }
  };
  f32x16 Oc0, Oc1;
#pragma unroll
  for (int r = 0; r < 16; r++) { Oc0[r] = 0.f; Oc1[r] = 0.f; }
  float m_run = -__builtin_inff(), l_run = 0.f;
  const u64* prow = PACKED ? (packw + qrow) : nullptr;
  issue_loads(0);
  write_tile(0);
  __syncthreads();
  int cur = 0;
  for (int kt = 0; kt < NKT; kt++) {
    if (kt + 1 < NKT) issue_loads(kt + 1);
    u64 pw;
    if constexpr (PACKED) {
      pw = prow[(size_t)kt * S_LEN];
    } else {
      pw = 0;
      for (int j = 0; j < 64; j++) {
        const bool pb = patget<MODE>(pat, qrow, kt * 64 + j) && (mask[kt * 64 + j] != 0);
        pw |= (u64)pb << j;
      }
    }
    const __bf16* Kl = Kls[cur];
    f32x16 p0, p1;
#pragma unroll
    for (int r = 0; r < 16; r++) { p0[r] = 0.f; p1[r] = 0.f; }
#pragma unroll
    for (int cc = 0; cc < 4; cc++) {
      const int g = (((2 * cc + hi) ^ (l32 & 7)) << 3);
      const bf16x8 k0 = *(const bf16x8*)&Kl[l32 * 64 + g];
      const bf16x8 k1 = *(const bf16x8*)&Kl[(32 + l32) * 64 + g];
      p0 = MFMA32(k0, aQ[cc], p0, 0, 0, 0);
      p1 = MFMA32(k1, aQ[cc], p1, 0, 0, 0);
    }
    float pm = p0[0];
#pragma unroll
    for (int r = 1; r < 16; r++) pm = fmaxf(pm, p0[r]);
#pragma unroll
    for (int r = 0; r < 16; r++) pm = fmaxf(pm, p1[r]);
    pm = fmaxf(pm, __shfl_xor(pm, 32));
    if (!__all(pm <= m_run + THRS)) {
      const float mn = fmaxf(m_run, pm);
      const float sf = EXP2(m_run - mn);
      m_run = mn;
      l_run *= sf;
      if (lane < 32) sfb[wv][l32] = sf;
#pragma unroll
      for (int rq = 0; rq < 4; rq++) {
        const f32x4 s4 = *(const f32x4*)&sfb[wv][rq * 8 + 4 * hi];
#pragma unroll
        for (int rr = 0; rr < 4; rr++) {
          Oc0[rq * 4 + rr] *= s4[rr];
          Oc1[rq * 4 + rr] *= s4[rr];
        }
      }
    }
    const u32 b0 = (u32)pw, b1 = (u32)(pw >> 32);
    const u32 w0 = hi ? ((b0 >> 4) | (b1 << 28)) : b0;
    const u32 w1 = hi ? (b1 >> 4) : b1;
    float ls = 0.f;
#pragma unroll
    for (int r = 0; r < 16; r++) {
      const int sp = (r & 3) + 8 * (r >> 2);
      float e0 = EXP2(p0[r] - m_run);
      float e1 = EXP2(p1[r] - m_run);
      const int t0 = (int)(w0 << (31 - sp)) >> 31;
      const int t1 = (int)(w1 << (31 - sp)) >> 31;
      e0 = __uint_as_float(__float_as_uint(e0) & (u32)t0);
      e1 = __uint_as_float(__float_as_uint(e1) & (u32)t1);
      p0[r] = e0; p1[r] = e1;
      ls += e0 + e1;
    }
    ls += __shfl_xor(ls, 32);
    l_run += ls;
    const __bf16* Vl = Vls[cur];
#pragma unroll
    for (int ks = 0; ks < 4; ks++) {
      const f32x16& ps = (ks < 2) ? p0 : p1;
      const int b = (ks & 1) * 8;
      u32 x0 = pk(ps[b + 0], ps[b + 1]), x1 = pk(ps[b + 2], ps[b + 3]);
      u32 y0 = pk(ps[b + 4], ps[b + 5]), y1 = pk(ps[b + 6], ps[b + 7]);
      plswap(x0, y0);
      plswap(x1, y1);
      PAW pa;
      pa.w = (u32x4v){x0, x1, y0, y1};
      const int g = (((2 * ks + hi) ^ (l32 & 7)) << 3);
      const bf16x8 v0 = *(const bf16x8*)&Vl[l32 * 64 + g];
      const bf16x8 v1 = *(const bf16x8*)&Vl[(32 + l32) * 64 + g];
      Oc0 = MFMA32(pa.h, v0, Oc0, 0, 0, 0);
      Oc1 = MFMA32(pa.h, v1, Oc1, 0, 0, 0);
    }
    if (kt + 1 < NKT) write_tile(cur ^ 1);
    __syncthreads();
    cur ^= 1;
  }
  const float linv = 1.0f / l_run;
  if (lane < 32) sfb[wv][l32] = linv;
  __syncthreads();
  float* ob = out + ((size_t)h * S_LEN + q0 + wv * WQ) * DHD;
#pragma unroll
  for (int rq = 0; rq < 4; rq++) {
    const f32x4 s4 = *(const f32x4*)&sfb[wv][rq * 8 + 4 * hi];
#pragma unroll
    for (int rr = 0; rr < 4; rr++) {
      const int r = rq * 4 + rr;
      const int qq = rr + 8 * rq + 4 * hi;
      ob[(size_t)qq * DHD + l32]      = Oc0[r] * s4[rr];
      ob[(size_t)qq * DHD + 32 + l32] = Oc1[r] * s4[rr];
    }
  }
}

__global__ void detect_kernel(const unsigned* __restrict__ p, int* __restrict__ flag) {
  __shared__ unsigned red[256];
  const int t = threadIdx.x;
  unsigned acc = 0;
  for (int i = t; i < 16384; i += 256) {
    const unsigned w = p[i];
    if (w == 0x3F800000u) acc |= 2u;
    else if (w & 0xFFFFFF00u) acc |= 1u;
  }
  red[t] = acc;
  __syncthreads();
  if (t == 0) {
    unsigned a = 0;
    for (int i = 0; i < 256; i++) a |= red[i];
    flag[0] = (a & 2u) ? 2 : ((a & 1u) ? 1 : 0);
  }
}

__global__ void pack_mask_kernel(const int* __restrict__ mask, u64* __restrict__ maskw) {
  const int w = threadIdx.x;
  u64 m = 0;
  for (int j = 0; j < 64; j++) m |= (u64)(mask[(w << 6) + j] != 0) << j;
  maskw[w] = m;
}

__global__ void pack_pat_kernel(const void* __restrict__ pat, const u64* __restrict__ maskw,
                                u64* __restrict__ packw, const int* __restrict__ flagp) {
  const int gid = blockIdx.x * 256 + threadIdx.x;
  const int q = gid >> 6, w = gid & 63;
  const int mode = flagp[0];
  u64 bits = 0;
  if (mode == 1) {
    const u64* p = (const u64*)((const unsigned char*)pat + ((size_t)q << 12) + (w << 6));
#pragma unroll
    for (int c = 0; c < 8; c++) {
      u64 v = p[c];
      v |= v >> 4; v |= v >> 2; v |= v >> 1;
      v &= 0x0101010101010101ull;
      bits |= ((v * 0x0102040810204080ull) >> 56) << (c * 8);
    }
  } else if (mode == 0) {
    const int4* p = (const int4*)((const int*)pat + ((size_t)q << 12) + ((size_t)w << 6));
#pragma unroll
    for (int c = 0; c < 16; c++) {
      const int4 x = p[c];
      bits |= (u64)(x.x != 0) << (c * 4);
      bits |= (u64)(x.y != 0) << (c * 4 + 1);
      bits |= (u64)(x.z != 0) << (c * 4 + 2);
      bits |= (u64)(x.w != 0) << (c * 4 + 3);
    }
  } else {
    const float4* p = (const float4*)((const float*)pat + ((size_t)q << 12) + ((size_t)w << 6));
#pragma unroll
    for (int c = 0; c < 16; c++) {
      const float4 x = p[c];
      bits |= (u64)(x.x != 0.0f) << (c * 4);
      bits |= (u64)(x.y != 0.0f) << (c * 4 + 1);
      bits |= (u64)(x.z != 0.0f) << (c * 4 + 2);
      bits |= (u64)(x.w != 0.0f) << (c * 4 + 3);
    }
  }
  packw[(size_t)w * S_LEN + q] = bits & maskw[w];
}

extern "C" void kernel_launch(void* const* d_in, const int* in_sizes, int n_in,
                              void* d_out, int out_size, void* d_ws, size_t ws_size,
                              hipStream_t stream) {
  (void)in_sizes; (void)n_in; (void)out_size;
  const float* Q  = (const float*)d_in[0];
  const float* K  = (const float*)d_in[1];
  const float* V  = (const float*)d_in[2];
  const void* pat = d_in[3];
  const int* mask = (const int*)d_in[4];
  float* out      = (float*)d_out;

  // workspace layout
  const size_t FLAG_OFF  = 0;
  const size_t MASKW_OFF = 24576;                      // 512 B (mid tier)
  const size_t PACKW_OFF = 32768;                      // 2 MB
  const size_t KC_OFF    = PACKW_OFF + (size_t)S_LEN * NKT * 8;       // +2 MB
  const size_t VC_OFF    = KC_OFF + (size_t)NH * NKT * 4096 * 2;      // +8 MB
  const size_t NEED_FULL = VC_OFF + (size_t)NH * NKT * 4096 * 2;      // ~18.9 MB
  const size_t NEED_MID  = PACKW_OFF + (size_t)S_LEN * NKT * 8;       // ~2.1 MB

  const dim3 grid(32 * NH, 1);   // 512 blocks, XCD-swizzled in-kernel

  if (ws_size >= NEED_FULL) {
    u64* packw = (u64*)((char*)d_ws + PACKW_OFF);
    __bf16* Kc = (__bf16*)((char*)d_ws + KC_OFF);
    __bf16* Vc = (__bf16*)((char*)d_ws + VC_OFF);
    prep_all<<<S_LEN + NKT * NH, 256, 0, stream>>>((const unsigned*)pat, mask, K, V,
                                                   packw, Kc, Vc);
    attn32c<<<grid, 512, 0, stream>>>(Q, Kc, Vc, packw, mask, out);
  } else if (ws_size >= NEED_MID) {
    int* flag  = (int*)((char*)d_ws + FLAG_OFF);
    u64* maskw = (u64*)((char*)d_ws + MASKW_OFF);
    u64* packw = (u64*)((char*)d_ws + PACKW_OFF);
    detect_kernel<<<1, 256, 0, stream>>>((const unsigned*)pat, flag);
    pack_mask_kernel<<<1, 64, 0, stream>>>(mask, maskw);
    pack_pat_kernel<<<(S_LEN * 64) / 256, 256, 0, stream>>>(pat, maskw, packw, flag);
    attn32<true, 0><<<grid, 256, 0, stream>>>(Q, K, V, packw, pat, mask, out);
  } else {
    attn32<false, 1><<<grid, 256, 0, stream>>>(Q, K, V, nullptr, pat, mask, out);
  }
}

// Round 9
// 94.782 us; speedup vs baseline: 1.2996x; 1.2996x over previous
//
#include <hip/hip_runtime.h>
#include <hip/hip_bf16.h>

#define S_LEN 4096
#define DHD   64
#define NH    16
#define NKT   64          // max k-tiles of 64
#define KVB   64
#define WQ    32          // q rows per wave
#define NW    4           // waves per block
#define QB    (WQ * NW)   // 128
// scale = 1/sqrt(64) = 0.125, folded with log2(e) so softmax runs in base-2 domain
#define QSCALE 0.18033688011112042f
#define THRS   8.656170245333781f   // defer-max threshold: 6 nats in log2 domain

typedef __bf16 bf16x8 __attribute__((ext_vector_type(8)));
typedef __bf16 bf16x4 __attribute__((ext_vector_type(4)));
typedef float  f32x16 __attribute__((ext_vector_type(16)));
typedef float  f32x4  __attribute__((ext_vector_type(4)));
typedef unsigned u32;
typedef unsigned u32x4v __attribute__((ext_vector_type(4)));
typedef unsigned long long u64;

#define MFMA32 __builtin_amdgcn_mfma_f32_32x32x16_bf16

// Guaranteed single-instruction 2^x (hw trans op). exp2f without fast-math lowers to an
// OCML libcall (~10 inst denorm-guarded) — that was ~half our VALU issue (R9 theory).
__device__ __forceinline__ float fexp2(float x) {
  float r;
  asm("v_exp_f32 %0, %1" : "=v"(r) : "v"(x));
  return r;
}
#define EXP2(x) fexp2(x)

// XOR swizzle (G4): element = row*64 + (((col>>3) ^ (row&7))<<3 | (col&7))
__device__ __forceinline__ int swz(int row, int col) {
  return row * 64 + ((((col >> 3) ^ (row & 7)) << 3) | (col & 7));
}

__device__ __forceinline__ u32 pk(float a, float b) {   // pack 2 f32 -> 2 bf16 (RNE)
  __bf16 x = (__bf16)a, y = (__bf16)b;
  u32 lo = (u32)__builtin_bit_cast(unsigned short, x);
  u32 hi = (u32)__builtin_bit_cast(unsigned short, y);
  return lo | (hi << 16);
}

__device__ __forceinline__ void gload16(const void* g, void* l) {
  __builtin_amdgcn_global_load_lds((const __attribute__((address_space(1))) void*)g,
                                   (__attribute__((address_space(3))) void*)l, 16, 0, 0);
}

// v_permlane32_swap_b32: x.hi <-> y.lo across the lane<32 / lane>=32 halves.
__device__ __forceinline__ void plswap(u32& x, u32& y) {
  asm("v_permlane32_swap_b32 %0, %1" : "+v"(x), "+v"(y));
}

union PAW { u32x4v w; bf16x8 h; };

template <int MODE>
__device__ __forceinline__ bool patget(const void* __restrict__ p, int q, int k) {
  const size_t idx = (size_t)q * S_LEN + k;
  if constexpr (MODE == 1) return ((const unsigned char*)p)[idx] != 0;
  else if constexpr (MODE == 0) return ((const int*)p)[idx] != 0;
  else return ((const float*)p)[idx] != 0.0f;
}

// ===================== compacted-key main kernel (2-tile unrolled, R7-proven) ============
// K/V pre-gathered (mask-surviving keys only), bf16, PRE-SWIZZLED tile layout:
//   Kc[h][kt][swz(kk,d)] = K[h][key(kt*64+kk)][d];  Vc[h][kt][swz(d,kk)] = V transposed.
// Tiles padded to an EVEN count; pad tiles are zero K/V with zero pattern bits (no-op).
// Pipeline: per pair, 2 pw loads + 8 gload_lds; counted vmcnt(10) + raw barriers (T4).
__global__ void __launch_bounds__(256, 2) attn32c(
    const float* __restrict__ Qg, const __bf16* __restrict__ Kc, const __bf16* __restrict__ Vc,
    const u64* __restrict__ packw,            // [w][q] bit j = pat(q, key(w*64+j))
    const int* __restrict__ mask, float* __restrict__ out) {
  __shared__ __align__(16) __bf16 Kls[4][KVB * DHD];
  __shared__ __align__(16) __bf16 Vls[4][DHD * KVB];
  __shared__ float sfb[NW][WQ];
  __shared__ int msum[NW];

  // XCD-chunked block swizzle: each XCD owns 2 consecutive heads (K/V L2-resident)
  const int gid = (blockIdx.x & 7) * 64 + (blockIdx.x >> 3);
  const int h = gid >> 5;
  const int q0 = (gid & 31) * QB;

  const int t = threadIdx.x, lane = t & 63, wv = t >> 6;
  const int l32 = lane & 31, hi = lane >> 5;
  const int qrow = q0 + wv * WQ + l32;

  // ---- self-compute active-key count from mask (16KB, L2-hot) ----
  int c = 0;
#pragma unroll
  for (int j = 0; j < 16; j++) c += (mask[t * 16 + j] != 0);
#pragma unroll
  for (int d = 1; d < 64; d <<= 1) c += __shfl_xor(c, d);
  if (lane == 0) msum[wv] = c;

  // Q B-fragments: aQ[cc] elem j = Q[qrow][cc*16 + hi*8 + j] * QSCALE
  bf16x8 aQ[4];
  {
    const float* qp = Qg + ((size_t)h * S_LEN + qrow) * DHD;
#pragma unroll
    for (int cc = 0; cc < 4; cc++) {
      float4 x = *(const float4*)(qp + cc * 16 + hi * 8);
      float4 y = *(const float4*)(qp + cc * 16 + hi * 8 + 4);
      bf16x8 f;
      f[0] = (__bf16)(x.x * QSCALE); f[1] = (__bf16)(x.y * QSCALE);
      f[2] = (__bf16)(x.z * QSCALE); f[3] = (__bf16)(x.w * QSCALE);
      f[4] = (__bf16)(y.x * QSCALE); f[5] = (__bf16)(y.y * QSCALE);
      f[6] = (__bf16)(y.z * QSCALE); f[7] = (__bf16)(y.w * QSCALE);
      aQ[cc] = f;
    }
  }
  bf16x8 onesf;
#pragma unroll
  for (int j = 0; j < 8; j++) onesf[j] = (__bf16)1.0f;
  f32x16 zv;
#pragma unroll
  for (int r = 0; r < 16; r++) zv[r] = 0.f;

  __syncthreads();
  const int nact = msum[0] + msum[1] + msum[2] + msum[3];
  const int nt = (nact + 63) >> 6;
  const int np = ((nt + 1) & ~1) >> 1;   // pairs

  const __bf16* Kb = Kc + (size_t)h * NKT * 4096;
  const __bf16* Vb = Vc + (size_t)h * NKT * 4096;

  auto stage = [&](int slot, int kt) {
    const __bf16* kbase = Kb + (size_t)kt * 4096;
    const __bf16* vbase = Vb + (size_t)kt * 4096;
#pragma unroll
    for (int i = 0; i < 2; i++) {
      const int j = wv * 2 + i;           // chunk 0..7 of 512 elems (1KB)
      gload16(kbase + j * 512 + lane * 8, &Kls[slot][j * 512]);
      gload16(vbase + j * 512 + lane * 8, &Vls[slot][j * 512]);
    }
  };

  f32x16 Oc0 = zv, Oc1 = zv, Ol = zv;
  float m_run = -__builtin_inff();
  const u64* prow = packw + qrow;

  __builtin_amdgcn_sched_barrier(0);   // pin all pre-loop waits above the pipeline
  // prologue: 2 pw loads + 8 gload_lds in flight
  u64 pwA = prow[0];
  u64 pwB = prow[(size_t)1 * S_LEN];
  stage(0, 0);
  stage(1, 1);

  for (int it = 0; it < np; it++) {
    const int buf = (it & 1) << 1;       // 0 or 2
    u64 pwA_n = 0, pwB_n = 0;
    if (it + 1 < np) {
      pwA_n = prow[(size_t)(2 * it + 2) * S_LEN];
      pwB_n = prow[(size_t)(2 * it + 3) * S_LEN];
      stage(buf ^ 2, 2 * it + 2);
      stage((buf ^ 2) + 1, 2 * it + 3);
      asm volatile("s_waitcnt vmcnt(10)" ::: "memory");  // prev pair's 10 vmem done
    } else {
      asm volatile("s_waitcnt vmcnt(0)" ::: "memory");
    }
    __builtin_amdgcn_s_barrier();
    __builtin_amdgcn_sched_barrier(0);   // rule #18

    const __bf16* KlA = Kls[buf];
    const __bf16* KlB = Kls[buf + 1];
    const __bf16* VlA = Vls[buf];
    const __bf16* VlB = Vls[buf + 1];

    // ---- S^T = K Q^T for BOTH tiles (16-MFMA cluster) ----
    f32x16 pA0, pA1, pB0, pB1;
    __builtin_amdgcn_s_setprio(1);
#pragma unroll
    for (int cc = 0; cc < 4; cc++) {
      const int g = (((2 * cc + hi) ^ (l32 & 7)) << 3);
      const bf16x8 kA0 = *(const bf16x8*)&KlA[l32 * 64 + g];
      const bf16x8 kA1 = *(const bf16x8*)&KlA[(32 + l32) * 64 + g];
      const bf16x8 kB0 = *(const bf16x8*)&KlB[l32 * 64 + g];
      const bf16x8 kB1 = *(const bf16x8*)&KlB[(32 + l32) * 64 + g];
      pA0 = MFMA32(kA0, aQ[cc], cc ? pA0 : zv, 0, 0, 0);
      pA1 = MFMA32(kA1, aQ[cc], cc ? pA1 : zv, 0, 0, 0);
      pB0 = MFMA32(kB0, aQ[cc], cc ? pB0 : zv, 0, 0, 0);
      pB1 = MFMA32(kB1, aQ[cc], cc ? pB1 : zv, 0, 0, 0);
    }
    __builtin_amdgcn_s_setprio(0);

    // ---- joint tree max over both tiles (pad tiles give score 0: harmless bound) ----
    float mx[32];
#pragma unroll
    for (int i = 0; i < 8; i++) {
      mx[i]      = fmaxf(pA0[2 * i], pA0[2 * i + 1]);
      mx[8 + i]  = fmaxf(pA1[2 * i], pA1[2 * i + 1]);
      mx[16 + i] = fmaxf(pB0[2 * i], pB0[2 * i + 1]);
      mx[24 + i] = fmaxf(pB1[2 * i], pB1[2 * i + 1]);
    }
#pragma unroll
    for (int s = 16; s >= 1; s >>= 1)
#pragma unroll
      for (int i = 0; i < s; i++) mx[i] = fmaxf(mx[i], mx[i + s]);
    const float pm = fmaxf(mx[0], __shfl_xor(mx[0], 32));

    if (!__all(pm <= m_run + THRS)) {   // defer-max (T13), once per PAIR
      const float mn = fmaxf(m_run, pm);
      const float sf = EXP2(m_run - mn);
      m_run = mn;
      if (lane < 32) sfb[wv][l32] = sf;
#pragma unroll
      for (int rq = 0; rq < 4; rq++) {   // transpose sf into C-layout rows (wave-private LDS)
        const f32x4 s4 = *(const f32x4*)&sfb[wv][rq * 8 + 4 * hi];
#pragma unroll
        for (int rr = 0; rr < 4; rr++) {
          Oc0[rq * 4 + rr] *= s4[rr];
          Oc1[rq * 4 + rr] *= s4[rr];
          Ol[rq * 4 + rr]  *= s4[rr];
        }
      }
    }

    // pattern bits, shifted for this lane half: element (ksub,sp) = bit 32*ksub + sp + 4*hi
    const u32 a0b = (u32)pwA, a1b = (u32)(pwA >> 32);
    const u32 wA0 = hi ? ((a0b >> 4) | (a1b << 28)) : a0b;
    const u32 wA1 = hi ? (a1b >> 4) : a1b;
    const u32 b0b = (u32)pwB, b1b = (u32)(pwB >> 32);
    const u32 wB0 = hi ? ((b0b >> 4) | (b1b << 28)) : b0b;
    const u32 wB1 = hi ? (b1b >> 4) : b1b;

#pragma unroll
    for (int r = 0; r < 16; r++) {
      const int sp = (r & 3) + 8 * (r >> 2);
      float eA0 = EXP2(pA0[r] - m_run);
      float eA1 = EXP2(pA1[r] - m_run);
      float eB0 = EXP2(pB0[r] - m_run);
      float eB1 = EXP2(pB1[r] - m_run);
      const int tA0 = (int)(wA0 << (31 - sp)) >> 31;
      const int tA1 = (int)(wA1 << (31 - sp)) >> 31;
      const int tB0 = (int)(wB0 << (31 - sp)) >> 31;
      const int tB1 = (int)(wB1 << (31 - sp)) >> 31;
      pA0[r] = __uint_as_float(__float_as_uint(eA0) & (u32)tA0);
      pA1[r] = __uint_as_float(__float_as_uint(eA1) & (u32)tA1);
      pB0[r] = __uint_as_float(__float_as_uint(eB0) & (u32)tB0);
      pB1[r] = __uint_as_float(__float_as_uint(eB1) & (u32)tB1);
    }

    // ---- P -> bf16 A-frags via pack + permlane32_swap; PV + l via MFMA-ones ----
    __builtin_amdgcn_s_setprio(1);
#pragma unroll
    for (int ks = 0; ks < 4; ks++) {
      const f32x16& ps = (ks < 2) ? pA0 : pA1;
      const int b = (ks & 1) * 8;
      u32 x0 = pk(ps[b + 0], ps[b + 1]), x1 = pk(ps[b + 2], ps[b + 3]);
      u32 y0 = pk(ps[b + 4], ps[b + 5]), y1 = pk(ps[b + 6], ps[b + 7]);
      plswap(x0, y0);
      plswap(x1, y1);
      PAW pa;
      pa.w = (u32x4v){x0, x1, y0, y1};
      const int g = (((2 * ks + hi) ^ (l32 & 7)) << 3);
      const bf16x8 v0 = *(const bf16x8*)&VlA[l32 * 64 + g];
      const bf16x8 v1 = *(const bf16x8*)&VlA[(32 + l32) * 64 + g];
      Oc0 = MFMA32(pa.h, v0, Oc0, 0, 0, 0);
      Oc1 = MFMA32(pa.h, v1, Oc1, 0, 0, 0);
      Ol  = MFMA32(pa.h, onesf, Ol, 0, 0, 0);
    }
#pragma unroll
    for (int ks = 0; ks < 4; ks++) {
      const f32x16& ps = (ks < 2) ? pB0 : pB1;
      const int b = (ks & 1) * 8;
      u32 x0 = pk(ps[b + 0], ps[b + 1]), x1 = pk(ps[b + 2], ps[b + 3]);
      u32 y0 = pk(ps[b + 4], ps[b + 5]), y1 = pk(ps[b + 6], ps[b + 7]);
      plswap(x0, y0);
      plswap(x1, y1);
      PAW pa;
      pa.w = (u32x4v){x0, x1, y0, y1};
      const int g = (((2 * ks + hi) ^ (l32 & 7)) << 3);
      const bf16x8 v0 = *(const bf16x8*)&VlB[l32 * 64 + g];
      const bf16x8 v1 = *(const bf16x8*)&VlB[(32 + l32) * 64 + g];
      Oc0 = MFMA32(pa.h, v0, Oc0, 0, 0, 0);
      Oc1 = MFMA32(pa.h, v1, Oc1, 0, 0, 0);
      Ol  = MFMA32(pa.h, onesf, Ol, 0, 0, 0);
    }
    __builtin_amdgcn_s_setprio(0);

    __builtin_amdgcn_s_barrier();   // all waves done reading this pair's buffers
    pwA = pwA_n;
    pwB = pwB_n;
  }

  // ---- epilogue: l already in C layout ----
  float* ob = out + ((size_t)h * S_LEN + q0 + wv * WQ) * DHD;
#pragma unroll
  for (int rq = 0; rq < 4; rq++) {
#pragma unroll
    for (int rr = 0; rr < 4; rr++) {
      const int r = rq * 4 + rr;
      const float linv = 1.0f / Ol[r];
      const int qq = rr + 8 * rq + 4 * hi;
      ob[(size_t)qq * DHD + l32]      = Oc0[r] * linv;
      ob[(size_t)qq * DHD + 32 + l32] = Oc1[r] * linv;
    }
  }
}

// ===================== single merged prep kernel =====================
// blocks [0, S_LEN): pattern-bit pack for q-row b (self dtype-detect, LDS-staged row).
// blocks [S_LEN, S_LEN+NKT*NH): K/V gather -> bf16 -> pre-swizzled tiles (+ zero pad tile).
__global__ void __launch_bounds__(256) prep_all(
    const unsigned* __restrict__ pat32, const int* __restrict__ mask,
    const float* __restrict__ K, const float* __restrict__ V,
    u64* __restrict__ packw, __bf16* __restrict__ Kc, __bf16* __restrict__ Vc) {
  __shared__ int idxs[S_LEN];          // 16 KB
  __shared__ int red8[8];
  __shared__ __align__(16) unsigned rowbuf[4096];   // 16 KB
  const int t = threadIdx.x, lane = t & 63, wv = t >> 6;

  // ---- active-key prefix list ----
  unsigned mb = 0;
#pragma unroll
  for (int j = 0; j < 16; j++) mb |= (unsigned)(mask[t * 16 + j] != 0) << j;
  const int cnt = __builtin_popcount(mb);
  int inc = cnt;
  for (int d = 1; d < 64; d <<= 1) {
    const int v = __shfl_up(inc, d);
    if (lane >= d) inc += v;
  }
  if (lane == 63) red8[wv] = inc;
  __syncthreads();
  int base = 0;
  for (int w = 0; w < wv; w++) base += red8[w];
  const int nact = red8[0] + red8[1] + red8[2] + red8[3];
  int pfx = base + inc - cnt;
#pragma unroll
  for (int j = 0; j < 16; j++)
    if ((mb >> j) & 1) idxs[pfx++] = t * 16 + j;
  __syncthreads();
  const int nt = (nact + 63) >> 6;
  const int nte = (nt + 1) & ~1;       // padded to even, <= 64

  if (blockIdx.x < S_LEN) {
    // ---- pattern pack ----
    const int q = blockIdx.x;
    unsigned acc = 0;
    for (int i = t; i < 4096; i += 256) {
      const unsigned w = pat32[i];
      if (w == 0x3F800000u) acc |= 2u;
      else if (w & 0xFFFFFF00u) acc |= 1u;
    }
    for (int d = 1; d < 64; d <<= 1) acc |= (unsigned)__shfl_xor((int)acc, d);
    if (lane == 0) red8[4 + wv] = (int)acc;
    __syncthreads();
    acc = (unsigned)(red8[4] | red8[5] | red8[6] | red8[7]);
    const int mode = (acc & 2u) ? 2 : ((acc & 1u) ? 1 : 0);

    if (mode == 1) {
      const uint4* src = (const uint4*)((const unsigned char*)pat32 + ((size_t)q << 12));
      ((uint4*)rowbuf)[t] = src[t];                         // 4096 B
    } else {
      const uint4* src = (const uint4*)(pat32 + ((size_t)q << 12));
#pragma unroll
      for (int i = 0; i < 4; i++) ((uint4*)rowbuf)[t + 256 * i] = src[t + 256 * i];  // 16 KB
    }
    __syncthreads();
    const unsigned char* rb = (const unsigned char*)rowbuf;
    const int nkw = nte * 64;          // include zero words for the pad tile
    for (int bs = 0; bs < nkw; bs += 256) {
      const int j = bs + t;
      bool pb = false;
      if (j < nact) {
        const int k = idxs[j];
        pb = (mode == 1) ? (rb[k] != 0) : (rowbuf[k] != 0);
      }
      const u64 b = __ballot(pb);
      if ((t & 63) == 0) packw[(size_t)(j >> 6) * S_LEN + q] = b;
    }
  } else {
    // ---- K/V gather ----
    const int bb = blockIdx.x - S_LEN;
    const int kt = bb & 63, h = bb >> 6;
    if (kt >= nte) return;             // pad tile (kt = nte-1 when nt odd) IS written (zeros)
    __bf16* Kd = Kc + ((size_t)(h * NKT + kt)) * 4096;
    __bf16* Vd = Vc + ((size_t)(h * NKT + kt)) * 4096;
    const float* Kb = K + (size_t)h * S_LEN * DHD;
    const float* Vb = V + (size_t)h * S_LEN * DHD;
#pragma unroll
    for (int i = 0; i < 4; i++) {
      const int u = t + 256 * i;
      const int kk = u >> 4, d = (u & 15) * 4;
      const int kg = kt * 64 + kk;
      float4 v = {0.f, 0.f, 0.f, 0.f};
      if (kg < nact) v = *(const float4*)(Kb + (size_t)idxs[kg] * DHD + d);
      bf16x4 b;
      b[0] = (__bf16)v.x; b[1] = (__bf16)v.y; b[2] = (__bf16)v.z; b[3] = (__bf16)v.w;
      *(bf16x4*)&Kd[swz(kk, d)] = b;
    }
#pragma unroll
    for (int i = 0; i < 2; i++) {
      const int u = t + 256 * i;
      const int kp = u & 31, d4 = u >> 5;
      const int g0 = kt * 64 + 2 * kp, g1 = g0 + 1;
      float4 a = {0.f, 0.f, 0.f, 0.f}, b = {0.f, 0.f, 0.f, 0.f};
      if (g0 < nact) a = *(const float4*)(Vb + (size_t)idxs[g0] * DHD + d4 * 4);
      if (g1 < nact) b = *(const float4*)(Vb + (size_t)idxs[g1] * DHD + d4 * 4);
      const float* A = reinterpret_cast<const float*>(&a);
      const float* B = reinterpret_cast<const float*>(&b);
#pragma unroll
      for (int j = 0; j < 4; j++) {
        *(u32*)&Vd[swz(d4 * 4 + j, 2 * kp)] = pk(A[j], B[j]);
      }
    }
  }
}

// ===================== fallback (R6, proven): full-key in-loop staging =====================
template <bool PACKED, int MODE>
__global__ void __launch_bounds__(256, 2) attn32(
    const float* __restrict__ Qg, const float* __restrict__ Kg, const float* __restrict__ Vg,
    const u64* __restrict__ packw, const void* __restrict__ pat, const int* __restrict__ mask,
    float* __restrict__ out) {
  __shared__ __align__(16) __bf16 Kls[2][KVB * DHD];
  __shared__ __align__(16) __bf16 Vls[2][DHD * KVB];
  __shared__ float sfb[NW][WQ];
  const int gid = (blockIdx.x & 7) * 64 + (blockIdx.x >> 3);
  const int h = gid >> 5;
  const int q0 = (gid & 31) * QB;
  const int t = threadIdx.x, lane = t & 63, wv = t >> 6;
  const int l32 = lane & 31, hi = lane >> 5;
  const int qrow = q0 + wv * WQ + l32;
  bf16x8 aQ[4];
  {
    const float* qp = Qg + ((size_t)h * S_LEN + qrow) * DHD;
#pragma unroll
    for (int cc = 0; cc < 4; cc++) {
      float4 x = *(const float4*)(qp + cc * 16 + hi * 8);
      float4 y = *(const float4*)(qp + cc * 16 + hi * 8 + 4);
      bf16x8 f;
      f[0] = (__bf16)(x.x * QSCALE); f[1] = (__bf16)(x.y * QSCALE);
      f[2] = (__bf16)(x.z * QSCALE); f[3] = (__bf16)(x.w * QSCALE);
      f[4] = (__bf16)(y.x * QSCALE); f[5] = (__bf16)(y.y * QSCALE);
      f[6] = (__bf16)(y.z * QSCALE); f[7] = (__bf16)(y.w * QSCALE);
      aQ[cc] = f;
    }
  }
  const float* Kb = Kg + (size_t)h * S_LEN * DHD;
  const float* Vb = Vg + (size_t)h * S_LEN * DHD;
  float4 kreg[4], vreg0[2], vreg1[2];
  auto issue_loads = [&](int kt) {
    const float* kbase = Kb + (size_t)kt * KVB * DHD;
    const float* vbase = Vb + (size_t)kt * KVB * DHD;
#pragma unroll
    for (int i = 0; i < 4; i++) {
      const int u = t + 256 * i;
      kreg[i] = *(const float4*)(kbase + (size_t)(u >> 4) * DHD + (u & 15) * 4);
    }
#pragma unroll
    for (int i = 0; i < 2; i++) {
      const int u = t + 256 * i;
      const int kp = u & 31, d4 = u >> 5;
      vreg0[i] = *(const float4*)(vbase + (size_t)(2 * kp) * DHD + d4 * 4);
      vreg1[i] = *(const float4*)(vbase + (size_t)(2 * kp + 1) * DHD + d4 * 4);
    }
  };
  auto write_tile = [&](int buf) {
    __bf16* Kd = Kls[buf];
    __bf16* Vd = Vls[buf];
#pragma unroll
    for (int i = 0; i < 4; i++) {
      const int u = t + 256 * i;
      const int kk = u >> 4, d = (u & 15) * 4;
      const float4 v = kreg[i];
      bf16x4 b;
      b[0] = (__bf16)v.x; b[1] = (__bf16)v.y; b[2] = (__bf16)v.z; b[3] = (__bf16)v.w;
      *(bf16x4*)&Kd[swz(kk, d)] = b;
    }
#pragma unroll
    for (int i = 0; i < 2; i++) {
      const int u = t + 256 * i;
      const int kp = u & 31, d4 = u >> 5;
      const float* A = reinterpret_cast<const float*>(&vreg0[i]);
      const float* B = reinterpret_cast<const float*>(&vreg1[i]);
#pragma unroll
      for (int j = 0; j < 4; j++) {
        *(u32*)&Vd[swz(d4 * 4 + j, 2 * kp)] = pk(A[j], B[j]);
      }
    }
  };
  f32x16 Oc0, Oc1;
#pragma unroll
  for (int r = 0; r < 16; r++) { Oc0[r] = 0.f; Oc1[r] = 0.f; }
  float m_run = -__builtin_inff(), l_run = 0.f;
  const u64* prow = PACKED ? (packw + qrow) : nullptr;
  issue_loads(0);
  write_tile(0);
  __syncthreads();
  int cur = 0;
  for (int kt = 0; kt < NKT; kt++) {
    if (kt + 1 < NKT) issue_loads(kt + 1);
    u64 pw;
    if constexpr (PACKED) {
      pw = prow[(size_t)kt * S_LEN];
    } else {
      pw = 0;
      for (int j = 0; j < 64; j++) {
        const bool pb = patget<MODE>(pat, qrow, kt * 64 + j) && (mask[kt * 64 + j] != 0);
        pw |= (u64)pb << j;
      }
    }
    const __bf16* Kl = Kls[cur];
    f32x16 p0, p1;
#pragma unroll
    for (int r = 0; r < 16; r++) { p0[r] = 0.f; p1[r] = 0.f; }
#pragma unroll
    for (int cc = 0; cc < 4; cc++) {
      const int g = (((2 * cc + hi) ^ (l32 & 7)) << 3);
      const bf16x8 k0 = *(const bf16x8*)&Kl[l32 * 64 + g];
      const bf16x8 k1 = *(const bf16x8*)&Kl[(32 + l32) * 64 + g];
      p0 = MFMA32(k0, aQ[cc], p0, 0, 0, 0);
      p1 = MFMA32(k1, aQ[cc], p1, 0, 0, 0);
    }
    float pm = p0[0];
#pragma unroll
    for (int r = 1; r < 16; r++) pm = fmaxf(pm, p0[r]);
#pragma unroll
    for (int r = 0; r < 16; r++) pm = fmaxf(pm, p1[r]);
    pm = fmaxf(pm, __shfl_xor(pm, 32));
    if (!__all(pm <= m_run + THRS)) {
      const float mn = fmaxf(m_run, pm);
      const float sf = EXP2(m_run - mn);
      m_run = mn;
      l_run *= sf;
      if (lane < 32) sfb[wv][l32] = sf;
#pragma unroll
      for (int rq = 0; rq < 4; rq++) {
        const f32x4 s4 = *(const f32x4*)&sfb[wv][rq * 8 + 4 * hi];
#pragma unroll
        for (int rr = 0; rr < 4; rr++) {
          Oc0[rq * 4 + rr] *= s4[rr];
          Oc1[rq * 4 + rr] *= s4[rr];
        }
      }
    }
    const u32 b0 = (u32)pw, b1 = (u32)(pw >> 32);
    const u32 w0 = hi ? ((b0 >> 4) | (b1 << 28)) : b0;
    const u32 w1 = hi ? (b1 >> 4) : b1;
    float ls = 0.f;
#pragma unroll
    for (int r = 0; r < 16; r++) {
      const int sp = (r & 3) + 8 * (r >> 2);
      float e0 = EXP2(p0[r] - m_run);
      float e1 = EXP2(p1[r] - m_run);
      const int t0 = (int)(w0 << (31 - sp)) >> 31;
      const int t1 = (int)(w1 << (31 - sp)) >> 31;
      e0 = __uint_as_float(__float_as_uint(e0) & (u32)t0);
      e1 = __uint_as_float(__float_as_uint(e1) & (u32)t1);
      p0[r] = e0; p1[r] = e1;
      ls += e0 + e1;
    }
    ls += __shfl_xor(ls, 32);
    l_run += ls;
    const __bf16* Vl = Vls[cur];
#pragma unroll
    for (int ks = 0; ks < 4; ks++) {
      const f32x16& ps = (ks < 2) ? p0 : p1;
      const int b = (ks & 1) * 8;
      u32 x0 = pk(ps[b + 0], ps[b + 1]), x1 = pk(ps[b + 2], ps[b + 3]);
      u32 y0 = pk(ps[b + 4], ps[b + 5]), y1 = pk(ps[b + 6], ps[b + 7]);
      plswap(x0, y0);
      plswap(x1, y1);
      PAW pa;
      pa.w = (u32x4v){x0, x1, y0, y1};
      const int g = (((2 * ks + hi) ^ (l32 & 7)) << 3);
      const bf16x8 v0 = *(const bf16x8*)&Vl[l32 * 64 + g];
      const bf16x8 v1 = *(const bf16x8*)&Vl[(32 + l32) * 64 + g];
      Oc0 = MFMA32(pa.h, v0, Oc0, 0, 0, 0);
      Oc1 = MFMA32(pa.h, v1, Oc1, 0, 0, 0);
    }
    if (kt + 1 < NKT) write_tile(cur ^ 1);
    __syncthreads();
    cur ^= 1;
  }
  const float linv = 1.0f / l_run;
  if (lane < 32) sfb[wv][l32] = linv;
  __syncthreads();
  float* ob = out + ((size_t)h * S_LEN + q0 + wv * WQ) * DHD;
#pragma unroll
  for (int rq = 0; rq < 4; rq++) {
    const f32x4 s4 = *(const f32x4*)&sfb[wv][rq * 8 + 4 * hi];
#pragma unroll
    for (int rr = 0; rr < 4; rr++) {
      const int r = rq * 4 + rr;
      const int qq = rr + 8 * rq + 4 * hi;
      ob[(size_t)qq * DHD + l32]      = Oc0[r] * s4[rr];
      ob[(size_t)qq * DHD + 32 + l32] = Oc1[r] * s4[rr];
    }
  }
}

__global__ void detect_kernel(const unsigned* __restrict__ p, int* __restrict__ flag) {
  __shared__ unsigned red[256];
  const int t = threadIdx.x;
  unsigned acc = 0;
  for (int i = t; i < 16384; i += 256) {
    const unsigned w = p[i];
    if (w == 0x3F800000u) acc |= 2u;
    else if (w & 0xFFFFFF00u) acc |= 1u;
  }
  red[t] = acc;
  __syncthreads();
  if (t == 0) {
    unsigned a = 0;
    for (int i = 0; i < 256; i++) a |= red[i];
    flag[0] = (a & 2u) ? 2 : ((a & 1u) ? 1 : 0);
  }
}

__global__ void pack_mask_kernel(const int* __restrict__ mask, u64* __restrict__ maskw) {
  const int w = threadIdx.x;
  u64 m = 0;
  for (int j = 0; j < 64; j++) m |= (u64)(mask[(w << 6) + j] != 0) << j;
  maskw[w] = m;
}

__global__ void pack_pat_kernel(const void* __restrict__ pat, const u64* __restrict__ maskw,
                                u64* __restrict__ packw, const int* __restrict__ flagp) {
  const int gid = blockIdx.x * 256 + threadIdx.x;
  const int q = gid >> 6, w = gid & 63;
  const int mode = flagp[0];
  u64 bits = 0;
  if (mode == 1) {
    const u64* p = (const u64*)((const unsigned char*)pat + ((size_t)q << 12) + (w << 6));
#pragma unroll
    for (int c = 0; c < 8; c++) {
      u64 v = p[c];
      v |= v >> 4; v |= v >> 2; v |= v >> 1;
      v &= 0x0101010101010101ull;
      bits |= ((v * 0x0102040810204080ull) >> 56) << (c * 8);
    }
  } else if (mode == 0) {
    const int4* p = (const int4*)((const int*)pat + ((size_t)q << 12) + ((size_t)w << 6));
#pragma unroll
    for (int c = 0; c < 16; c++) {
      const int4 x = p[c];
      bits |= (u64)(x.x != 0) << (c * 4);
      bits |= (u64)(x.y != 0) << (c * 4 + 1);
      bits |= (u64)(x.z != 0) << (c * 4 + 2);
      bits |= (u64)(x.w != 0) << (c * 4 + 3);
    }
  } else {
    const float4* p = (const float4*)((const float*)pat + ((size_t)q << 12) + ((size_t)w << 6));
#pragma unroll
    for (int c = 0; c < 16; c++) {
      const float4 x = p[c];
      bits |= (u64)(x.x != 0.0f) << (c * 4);
      bits |= (u64)(x.y != 0.0f) << (c * 4 + 1);
      bits |= (u64)(x.z != 0.0f) << (c * 4 + 2);
      bits |= (u64)(x.w != 0.0f) << (c * 4 + 3);
    }
  }
  packw[(size_t)w * S_LEN + q] = bits & maskw[w];
}

extern "C" void kernel_launch(void* const* d_in, const int* in_sizes, int n_in,
                              void* d_out, int out_size, void* d_ws, size_t ws_size,
                              hipStream_t stream) {
  (void)in_sizes; (void)n_in; (void)out_size;
  const float* Q  = (const float*)d_in[0];
  const float* K  = (const float*)d_in[1];
  const float* V  = (const float*)d_in[2];
  const void* pat = d_in[3];
  const int* mask = (const int*)d_in[4];
  float* out      = (float*)d_out;

  // workspace layout
  const size_t FLAG_OFF  = 0;
  const size_t MASKW_OFF = 24576;                      // 512 B (mid tier)
  const size_t PACKW_OFF = 32768;                      // 2 MB
  const size_t KC_OFF    = PACKW_OFF + (size_t)S_LEN * NKT * 8;       // +2 MB
  const size_t VC_OFF    = KC_OFF + (size_t)NH * NKT * 4096 * 2;      // +8 MB
  const size_t NEED_FULL = VC_OFF + (size_t)NH * NKT * 4096 * 2;      // ~18.9 MB
  const size_t NEED_MID  = PACKW_OFF + (size_t)S_LEN * NKT * 8;       // ~2.1 MB

  const dim3 grid(32 * NH, 1);   // 512 blocks, XCD-swizzled in-kernel

  if (ws_size >= NEED_FULL) {
    u64* packw = (u64*)((char*)d_ws + PACKW_OFF);
    __bf16* Kc = (__bf16*)((char*)d_ws + KC_OFF);
    __bf16* Vc = (__bf16*)((char*)d_ws + VC_OFF);
    prep_all<<<S_LEN + NKT * NH, 256, 0, stream>>>((const unsigned*)pat, mask, K, V,
                                                   packw, Kc, Vc);
    attn32c<<<grid, 256, 0, stream>>>(Q, Kc, Vc, packw, mask, out);
  } else if (ws_size >= NEED_MID) {
    int* flag  = (int*)((char*)d_ws + FLAG_OFF);
    u64* maskw = (u64*)((char*)d_ws + MASKW_OFF);
    u64* packw = (u64*)((char*)d_ws + PACKW_OFF);
    detect_kernel<<<1, 256, 0, stream>>>((const unsigned*)pat, flag);
    pack_mask_kernel<<<1, 64, 0, stream>>>(mask, maskw);
    pack_pat_kernel<<<(S_LEN * 64) / 256, 256, 0, stream>>>(pat, maskw, packw, flag);
    attn32<true, 0><<<grid, 256, 0, stream>>>(Q, K, V, packw, pat, mask, out);
  } else {
    attn32<false, 1><<<grid, 256, 0, stream>>>(Q, K, V, nullptr, pat, mask, out);
  }
}